// Round 1
// baseline (4738.505 us; speedup 1.0000x reference)
//
#include <hip/hip_runtime.h>
#include <hip/hip_bf16.h>

#define TL 2048
#define NB 64
#define NH 64
#define NLAY 10
#define NRESU 3
#define RING_STEPS 128
#define GB 16
#define NGRP 4

typedef float f32x4 __attribute__((ext_vector_type(4)));
typedef short bhalf8 __attribute__((ext_vector_type(8)));
typedef short bhalf4 __attribute__((ext_vector_type(4)));

__device__ __forceinline__ unsigned short f2bf(float f) {
    unsigned u = __float_as_uint(f);
    unsigned r = u + 0x7fffu + ((u >> 16) & 1u);
    return (unsigned short)(r >> 16);
}
__device__ __forceinline__ float bf2f(unsigned short h) {
    return __uint_as_float(((unsigned)h) << 16);
}
__device__ __forceinline__ float fast_sigmoid(float x) {
    return __builtin_amdgcn_rcpf(1.0f + __expf(-x));
}
__device__ __forceinline__ float fast_tanh(float x) {
    float e = __expf(2.0f * x);
    return 1.0f - 2.0f * __builtin_amdgcn_rcpf(e + 1.0f);
}

// ---------------- frontend: 1x1 conv 4->32 relu, 1x1 conv 32->64 relu ----------------
// in: [NB][TL][4]  out x0: [NB][64][TL]
__global__ __launch_bounds__(256) void k_frontend(
    const float* __restrict__ in,
    const float* __restrict__ c1w, const float* __restrict__ c1b,
    const float* __restrict__ c2w, const float* __restrict__ c2b,
    float* __restrict__ x0)
{
    __shared__ float s_c1w[128];
    __shared__ float s_c1b[32];
    __shared__ float s_c2w[64 * 33];
    __shared__ float s_c2b[64];
    __shared__ float h1[64 * 33];
    __shared__ float ot[64 * 65];
    int tid = threadIdx.x;
    int b = blockIdx.x >> 5;
    int l0 = (blockIdx.x & 31) << 6;
    if (tid < 128) s_c1w[tid] = c1w[tid];
    if (tid < 32) s_c1b[tid] = c1b[tid];
    if (tid < 64) s_c2b[tid] = c2b[tid];
    for (int r = tid; r < 2048; r += 256) s_c2w[(r >> 5) * 33 + (r & 31)] = c2w[r];
    __syncthreads();
    if (tid < 64) {
        const float* ip = in + ((size_t)b * TL + l0 + tid) * 4;
        float x0v = ip[0], x1 = ip[1], x2 = ip[2], x3 = ip[3];
#pragma unroll
        for (int o = 0; o < 32; o++) {
            float a = s_c1w[o * 4 + 0] * x0v + s_c1w[o * 4 + 1] * x1 +
                      s_c1w[o * 4 + 2] * x2 + s_c1w[o * 4 + 3] * x3 + s_c1b[o];
            h1[tid * 33 + o] = fmaxf(a, 0.0f);
        }
    }
    __syncthreads();
    {
        int o = tid & 63, lg = tid >> 6;
#pragma unroll
        for (int j = 0; j < 16; j++) {
            int l = lg * 16 + j;
            float a = s_c2b[o];
#pragma unroll
            for (int i = 0; i < 32; i++) a += h1[l * 33 + i] * s_c2w[o * 33 + i];
            ot[o * 65 + l] = fmaxf(a, 0.0f);
        }
    }
    __syncthreads();
    for (int r = 0; r < 16; r++) {
        int idx = tid + 256 * r;
        int c = idx >> 6, l = idx & 63;
        x0[((size_t)b * 64 + c) * TL + l0 + l] = ot[c * 65 + l];
    }
}

// ---------------- residual conv k=11 pad=5, BN+ReLU fused on input load ----------------
// in/out: [NB][64][TL].  accumulate: out += conv result (plus bias), else out = conv+bias.
__global__ __launch_bounds__(256) void k_resconv(
    const float* __restrict__ in, float* __restrict__ out,
    const float* __restrict__ w, const float* __restrict__ bias,
    const float* __restrict__ bg, const float* __restrict__ bb,
    const float* __restrict__ bm, const float* __restrict__ bv,
    int accumulate)
{
    __shared__ float sscale[64], sshift[64];
    __shared__ float ht[64 * 139];
    int tid = threadIdx.x;
    int b = blockIdx.x >> 4;
    int l0 = (blockIdx.x & 15) << 7;
    if (tid < 64) {
        float sc = bg[tid] * rsqrtf(bv[tid] + 1e-5f);
        sscale[tid] = sc;
        sshift[tid] = bb[tid] - bm[tid] * sc;
    }
    __syncthreads();
    for (int r = 0; r < 35; r++) {
        int idx = tid + 256 * r;
        if (idx < 64 * 138) {
            int i = idx / 138, ll = idx - i * 138;
            int l = l0 - 5 + ll;
            float v = 0.0f;
            if (l >= 0 && l < TL) v = in[((size_t)b * 64 + i) * TL + l];
            ht[i * 139 + ll] = fmaxf(v * sscale[i] + sshift[i], 0.0f);
        }
    }
    __syncthreads();
    int o = tid & 63, lq = tid >> 6;
    float acc[32];
#pragma unroll
    for (int j = 0; j < 32; j++) acc[j] = 0.0f;
    const float* wp = w + o * 704;
    for (int i = 0; i < 64; i++) {
        float wr[11];
#pragma unroll
        for (int k = 0; k < 11; k++) wr[k] = wp[i * 11 + k];
        float hr[42];
        const float* hp = ht + i * 139 + lq * 32;
#pragma unroll
        for (int k = 0; k < 42; k++) hr[k] = hp[k];
#pragma unroll
        for (int k = 0; k < 11; k++)
#pragma unroll
            for (int j = 0; j < 32; j++) acc[j] += hr[k + j] * wr[k];
    }
    float bsv = bias[o];
    float* op = out + ((size_t)b * 64 + o) * TL + l0 + lq * 32;
    if (accumulate) {
#pragma unroll
        for (int j = 0; j < 32; j++) op[j] += acc[j] + bsv;
    } else {
#pragma unroll
        for (int j = 0; j < 32; j++) op[j] = acc[j] + bsv;
    }
}

// ---------------- transpose [NB][64][TL] -> [TL][NB][64] ----------------
__global__ __launch_bounds__(256) void k_transpose(
    const float* __restrict__ x0, float* __restrict__ X)
{
    __shared__ float t[64 * 65];
    int tid = threadIdx.x;
    int b = blockIdx.x >> 5;
    int t0 = (blockIdx.x & 31) << 6;
    for (int r = 0; r < 16; r++) {
        int idx = tid + 256 * r;
        int c = idx >> 6, tt = idx & 63;
        t[c * 65 + tt] = x0[((size_t)b * 64 + c) * TL + t0 + tt];
    }
    __syncthreads();
    for (int r = 0; r < 16; r++) {
        int idx = tid + 256 * r;
        int tt = idx >> 6, c = idx & 63;
        X[((size_t)(t0 + tt)) * (NB * NH) + b * 64 + c] = t[c * 65 + tt];
    }
}

// ---------------- pipelined 10-layer LSTM ----------------
// 40 active WGs: (layer, group of 16 batches). Weights live in VGPRs (split bf16 hi/lo,
// 3-term MFMA ~= fp32). Inter-layer handoff through ring buffer with agent-scope atomics.
__global__ __launch_bounds__(256, 1) void k_lstm(
    const float* __restrict__ X0,
    const float* __restrict__ w_ih, const float* __restrict__ w_hh,
    const float* __restrict__ b_ih, const float* __restrict__ b_hh,
    float* __restrict__ ring, float* __restrict__ final_h, int* prog)
{
    int bid = blockIdx.x;
    int grp = bid & 7;
    int layer = bid >> 3;
    if (grp >= NGRP || layer >= NLAY) return;   // XCD-affinity spacing: group g stays on bid%8==g
    int b0 = grp * GB;
    int tid = threadIdx.x;
    int wv = tid >> 6, lane = tid & 63;
    int l15 = lane & 15, l4 = lane >> 4;

    __shared__ __align__(16) unsigned short XH[16 * 136];
    __shared__ __align__(16) unsigned short XL[16 * 136];

    // --- load weight fragments into registers (persist across all 2048 steps) ---
    bhalf8 Bh[4][4], Bl[4][4];
    float bias_v[4];
#pragma unroll
    for (int nt = 0; nt < 4; nt++) {
        int n = (nt * 4 + wv) * 16 + l15;     // gate row: nt*64 + u
        const float* rih = w_ih + ((size_t)layer * 256 + n) * 64;
        const float* rhh = w_hh + ((size_t)layer * 256 + n) * 64;
        bias_v[nt] = b_ih[layer * 256 + n] + b_hh[layer * 256 + n];
#pragma unroll
        for (int kt = 0; kt < 4; kt++) {
#pragma unroll
            for (int j = 0; j < 8; j++) {
                int k = kt * 32 + l4 * 8 + j;
                float v = (k < 64) ? rih[k] : rhh[k - 64];
                unsigned short hb = f2bf(v);
                float lo = v - bf2f(hb);
                Bh[nt][kt][j] = (short)hb;
                Bl[nt][kt][j] = (short)f2bf(lo);
            }
        }
    }

    // zero initial h (cols 64..127)
    for (int idx = tid; idx < 1024; idx += 256) {
        int rw = idx >> 6, cc = 64 + (idx & 63);
        XH[rw * 136 + cc] = 0;
        XL[rw * 136 + cc] = 0;
    }
    float cst[4] = {0.f, 0.f, 0.f, 0.f};

    int self = layer * NGRP + grp;
    int* p_self = prog + self * 32;
    int* p_prev = prog + (self - NGRP) * 32;
    int* p_next = prog + (self + NGRP) * 32;
    int cached_prev = 0, cached_next = 0;
    int u = wv * 16 + l15;

    for (int t = 0; t < TL; t++) {
        if (tid == 0) {
            if (layer > 0 && cached_prev < t + 1) {
                int v;
                while ((v = __hip_atomic_load(p_prev, __ATOMIC_ACQUIRE, __HIP_MEMORY_SCOPE_AGENT)) < t + 1)
                    __builtin_amdgcn_s_sleep(2);
                cached_prev = v;
            }
            if (layer < NLAY - 1 && t >= RING_STEPS && cached_next < t - RING_STEPS + 1) {
                int v;
                while ((v = __hip_atomic_load(p_next, __ATOMIC_ACQUIRE, __HIP_MEMORY_SCOPE_AGENT)) < t - RING_STEPS + 1)
                    __builtin_amdgcn_s_sleep(2);
                cached_next = v;
            }
        }
        __syncthreads();

        // stage x_t (16 batches x 64) into LDS as hi/lo bf16
        {
            int idx = tid * 4;
            int brow = idx >> 6, cc = idx & 63;
            float v[4];
            if (layer == 0) {
                const float* src = X0 + ((size_t)t * NB + b0) * NH + idx;
#pragma unroll
                for (int j = 0; j < 4; j++) v[j] = src[j];
            } else {
                const unsigned* src = (const unsigned*)(ring +
                    ((size_t)(layer - 1) * RING_STEPS + (t & (RING_STEPS - 1))) * (NB * NH) + b0 * NH) + idx;
#pragma unroll
                for (int j = 0; j < 4; j++)
                    v[j] = __uint_as_float(__hip_atomic_load((unsigned*)(src + j), __ATOMIC_RELAXED, __HIP_MEMORY_SCOPE_AGENT));
            }
            bhalf4 hv, lv;
#pragma unroll
            for (int j = 0; j < 4; j++) {
                unsigned short hb = f2bf(v[j]);
                hv[j] = (short)hb;
                lv[j] = (short)f2bf(v[j] - bf2f(hb));
            }
            *(bhalf4*)&XH[brow * 136 + cc] = hv;
            *(bhalf4*)&XL[brow * 136 + cc] = lv;
        }
        __syncthreads();

        // gates[16,256] = Xcat(hi+lo) @ Wcat(hi+lo)^T   (3-term split precision)
        f32x4 a0 = {0, 0, 0, 0}, a1 = {0, 0, 0, 0}, a2 = {0, 0, 0, 0}, a3 = {0, 0, 0, 0};
#pragma unroll
        for (int kt = 0; kt < 4; kt++) {
            int aoff = l15 * 136 + kt * 32 + l4 * 8;
            bhalf8 Ah = *(const bhalf8*)&XH[aoff];
            bhalf8 Al = *(const bhalf8*)&XL[aoff];
            a0 = __builtin_amdgcn_mfma_f32_16x16x32_bf16(Ah, Bh[0][kt], a0, 0, 0, 0);
            a1 = __builtin_amdgcn_mfma_f32_16x16x32_bf16(Ah, Bh[1][kt], a1, 0, 0, 0);
            a2 = __builtin_amdgcn_mfma_f32_16x16x32_bf16(Ah, Bh[2][kt], a2, 0, 0, 0);
            a3 = __builtin_amdgcn_mfma_f32_16x16x32_bf16(Ah, Bh[3][kt], a3, 0, 0, 0);
            a0 = __builtin_amdgcn_mfma_f32_16x16x32_bf16(Al, Bh[0][kt], a0, 0, 0, 0);
            a1 = __builtin_amdgcn_mfma_f32_16x16x32_bf16(Al, Bh[1][kt], a1, 0, 0, 0);
            a2 = __builtin_amdgcn_mfma_f32_16x16x32_bf16(Al, Bh[2][kt], a2, 0, 0, 0);
            a3 = __builtin_amdgcn_mfma_f32_16x16x32_bf16(Al, Bh[3][kt], a3, 0, 0, 0);
            a0 = __builtin_amdgcn_mfma_f32_16x16x32_bf16(Ah, Bl[0][kt], a0, 0, 0, 0);
            a1 = __builtin_amdgcn_mfma_f32_16x16x32_bf16(Ah, Bl[1][kt], a1, 0, 0, 0);
            a2 = __builtin_amdgcn_mfma_f32_16x16x32_bf16(Ah, Bl[2][kt], a2, 0, 0, 0);
            a3 = __builtin_amdgcn_mfma_f32_16x16x32_bf16(Ah, Bl[3][kt], a3, 0, 0, 0);
        }
        __syncthreads();  // A-frag LDS reads complete before h rewrite

        // lane-local nonlinearity: this lane owns gates (i,f,g,o) for u, batches l4*4+r
        float hv4[4];
#pragma unroll
        for (int r = 0; r < 4; r++) {
            float gi = a0[r] + bias_v[0];
            float gf = a1[r] + bias_v[1];
            float gg = a2[r] + bias_v[2];
            float go = a3[r] + bias_v[3];
            float c = fast_sigmoid(gf) * cst[r] + fast_sigmoid(gi) * fast_tanh(gg);
            cst[r] = c;
            hv4[r] = fast_sigmoid(go) * fast_tanh(c);
        }
#pragma unroll
        for (int r = 0; r < 4; r++) {
            int row = l4 * 4 + r;
            unsigned short hb = f2bf(hv4[r]);
            XH[row * 136 + 64 + u] = hb;
            XL[row * 136 + 64 + u] = f2bf(hv4[r] - bf2f(hb));
        }
        if (layer < NLAY - 1) {
            unsigned* dst = (unsigned*)(ring +
                ((size_t)layer * RING_STEPS + (t & (RING_STEPS - 1))) * (NB * NH));
#pragma unroll
            for (int r = 0; r < 4; r++) {
                int bglob = b0 + l4 * 4 + r;
                __hip_atomic_store(dst + bglob * NH + u, __float_as_uint(hv4[r]),
                                   __ATOMIC_RELAXED, __HIP_MEMORY_SCOPE_AGENT);
            }
        } else if (t == TL - 1) {
#pragma unroll
            for (int r = 0; r < 4; r++)
                final_h[(b0 + l4 * 4 + r) * NH + u] = hv4[r];
        }
        __syncthreads();
        if (tid == 0 && (t & 3) == 3)
            __hip_atomic_store(p_self, t + 1, __ATOMIC_RELEASE, __HIP_MEMORY_SCOPE_AGENT);
    }
}

// ---------------- head: logits + log_softmax ----------------
__global__ void k_head(const float* __restrict__ fh, const float* __restrict__ ow,
                       const float* __restrict__ ob, float* __restrict__ out)
{
    int b = threadIdx.x;
    if (b >= NB) return;
    const float* h = fh + b * NH;
    float l0 = ob[0], l1 = ob[1];
    for (int uu = 0; uu < 64; uu++) { l0 += h[uu] * ow[uu * 2]; l1 += h[uu] * ow[uu * 2 + 1]; }
    float m = fmaxf(l0, l1);
    float s = expf(l0 - m) + expf(l1 - m);
    float ls = m + logf(s);
    out[b * 2] = l0 - ls;
    out[b * 2 + 1] = l1 - ls;
}

extern "C" void kernel_launch(void* const* d_in, const int* in_sizes, int n_in,
                              void* d_out, int out_size, void* d_ws, size_t ws_size,
                              hipStream_t stream) {
    const float* input = (const float*)d_in[0];
    const float* c1w = (const float*)d_in[2];
    const float* c1b = (const float*)d_in[3];
    const float* c2w = (const float*)d_in[4];
    const float* c2b = (const float*)d_in[5];
    const float* bn1g = (const float*)d_in[6];
    const float* bn1b = (const float*)d_in[7];
    const float* bn1m = (const float*)d_in[8];
    const float* bn1v = (const float*)d_in[9];
    const float* rw1 = (const float*)d_in[10];
    const float* rb1 = (const float*)d_in[11];
    const float* bn2g = (const float*)d_in[12];
    const float* bn2b = (const float*)d_in[13];
    const float* bn2m = (const float*)d_in[14];
    const float* bn2v = (const float*)d_in[15];
    const float* rw2 = (const float*)d_in[16];
    const float* rb2 = (const float*)d_in[17];
    const float* wih = (const float*)d_in[18];
    const float* whh = (const float*)d_in[19];
    const float* bih = (const float*)d_in[20];
    const float* bhh = (const float*)d_in[21];
    const float* outw = (const float*)d_in[22];
    const float* outb = (const float*)d_in[23];

    float* ws = (float*)d_ws;
    float* x0buf = ws;                       // [NB][64][TL]        8,388,608 f
    float* t1buf = x0buf + 8388608;          // [NB][64][TL]        8,388,608 f
    float* Xbuf  = t1buf + 8388608;          // [TL][NB][NH]        8,388,608 f
    float* ringb = Xbuf + 8388608;           // [9][128][4096]      4,718,592 f
    float* fhbuf = ringb + 4718592;          // [NB][NH]            4,096 f
    int*   progb = (int*)(fhbuf + 4096);     // 40 counters, stride 32 ints

    hipMemsetAsync(progb, 0, NLAY * NGRP * 32 * sizeof(int), stream);

    k_frontend<<<2048, 256, 0, stream>>>(input, c1w, c1b, c2w, c2b, x0buf);
    for (int uu = 0; uu < NRESU; uu++) {
        k_resconv<<<1024, 256, 0, stream>>>(x0buf, t1buf, rw1 + uu * 64 * 64 * 11, rb1 + uu * 64,
                                            bn1g + uu * 64, bn1b + uu * 64, bn1m + uu * 64, bn1v + uu * 64, 0);
        k_resconv<<<1024, 256, 0, stream>>>(t1buf, x0buf, rw2 + uu * 64 * 64 * 11, rb2 + uu * 64,
                                            bn2g + uu * 64, bn2b + uu * 64, bn2m + uu * 64, bn2v + uu * 64, 1);
    }
    k_transpose<<<2048, 256, 0, stream>>>(x0buf, Xbuf);
    k_lstm<<<76, 256, 0, stream>>>(Xbuf, wih, whh, bih, bhh, ringb, fhbuf, progb);
    k_head<<<1, 64, 0, stream>>>(fhbuf, outw, outb, (float*)d_out);
}

// Round 2
// 3449.134 us; speedup vs baseline: 1.3738x; 1.3738x over previous
//
#include <hip/hip_runtime.h>
#include <hip/hip_bf16.h>

#define TL 2048
#define NB 64
#define NH 64
#define NLAY 10
#define NRESU 3
#define RING_STEPS 128
#define GB 16
#define NGRP 4

typedef float f32x4 __attribute__((ext_vector_type(4)));
typedef short bhalf8 __attribute__((ext_vector_type(8)));
typedef short bhalf4 __attribute__((ext_vector_type(4)));

__device__ __forceinline__ unsigned short f2bf(float f) {
    unsigned u = __float_as_uint(f);
    unsigned r = u + 0x7fffu + ((u >> 16) & 1u);
    return (unsigned short)(r >> 16);
}
__device__ __forceinline__ float bf2f(unsigned short h) {
    return __uint_as_float(((unsigned)h) << 16);
}
__device__ __forceinline__ float fast_sigmoid(float x) {
    return __builtin_amdgcn_rcpf(1.0f + __expf(-x));
}
__device__ __forceinline__ float fast_tanh(float x) {
    float e = __expf(2.0f * x);
    return 1.0f - 2.0f * __builtin_amdgcn_rcpf(e + 1.0f);
}

// ---------------- frontend: 1x1 conv 4->32 relu, 1x1 conv 32->64 relu ----------------
__global__ __launch_bounds__(256) void k_frontend(
    const float* __restrict__ in,
    const float* __restrict__ c1w, const float* __restrict__ c1b,
    const float* __restrict__ c2w, const float* __restrict__ c2b,
    float* __restrict__ x0)
{
    __shared__ float s_c1w[128];
    __shared__ float s_c1b[32];
    __shared__ float s_c2w[64 * 33];
    __shared__ float s_c2b[64];
    __shared__ float h1[64 * 33];
    __shared__ float ot[64 * 65];
    int tid = threadIdx.x;
    int b = blockIdx.x >> 5;
    int l0 = (blockIdx.x & 31) << 6;
    if (tid < 128) s_c1w[tid] = c1w[tid];
    if (tid < 32) s_c1b[tid] = c1b[tid];
    if (tid < 64) s_c2b[tid] = c2b[tid];
    for (int r = tid; r < 2048; r += 256) s_c2w[(r >> 5) * 33 + (r & 31)] = c2w[r];
    __syncthreads();
    if (tid < 64) {
        const float* ip = in + ((size_t)b * TL + l0 + tid) * 4;
        float x0v = ip[0], x1 = ip[1], x2 = ip[2], x3 = ip[3];
#pragma unroll
        for (int o = 0; o < 32; o++) {
            float a = s_c1w[o * 4 + 0] * x0v + s_c1w[o * 4 + 1] * x1 +
                      s_c1w[o * 4 + 2] * x2 + s_c1w[o * 4 + 3] * x3 + s_c1b[o];
            h1[tid * 33 + o] = fmaxf(a, 0.0f);
        }
    }
    __syncthreads();
    {
        int o = tid & 63, lg = tid >> 6;
#pragma unroll
        for (int j = 0; j < 16; j++) {
            int l = lg * 16 + j;
            float a = s_c2b[o];
#pragma unroll
            for (int i = 0; i < 32; i++) a += h1[l * 33 + i] * s_c2w[o * 33 + i];
            ot[o * 65 + l] = fmaxf(a, 0.0f);
        }
    }
    __syncthreads();
    for (int r = 0; r < 16; r++) {
        int idx = tid + 256 * r;
        int c = idx >> 6, l = idx & 63;
        x0[((size_t)b * 64 + c) * TL + l0 + l] = ot[c * 65 + l];
    }
}

// ---------------- residual conv k=11 pad=5, BN+ReLU fused on input load ----------------
__global__ __launch_bounds__(256) void k_resconv(
    const float* __restrict__ in, float* __restrict__ out,
    const float* __restrict__ w, const float* __restrict__ bias,
    const float* __restrict__ bg, const float* __restrict__ bb,
    const float* __restrict__ bm, const float* __restrict__ bv,
    int accumulate)
{
    __shared__ float sscale[64], sshift[64];
    __shared__ float ht[64 * 139];
    int tid = threadIdx.x;
    int b = blockIdx.x >> 4;
    int l0 = (blockIdx.x & 15) << 7;
    if (tid < 64) {
        float sc = bg[tid] * rsqrtf(bv[tid] + 1e-5f);
        sscale[tid] = sc;
        sshift[tid] = bb[tid] - bm[tid] * sc;
    }
    __syncthreads();
    for (int r = 0; r < 35; r++) {
        int idx = tid + 256 * r;
        if (idx < 64 * 138) {
            int i = idx / 138, ll = idx - i * 138;
            int l = l0 - 5 + ll;
            float v = 0.0f;
            if (l >= 0 && l < TL) v = in[((size_t)b * 64 + i) * TL + l];
            ht[i * 139 + ll] = fmaxf(v * sscale[i] + sshift[i], 0.0f);
        }
    }
    __syncthreads();
    int o = tid & 63, lq = tid >> 6;
    float acc[32];
#pragma unroll
    for (int j = 0; j < 32; j++) acc[j] = 0.0f;
    const float* wp = w + o * 704;
    for (int i = 0; i < 64; i++) {
        float wr[11];
#pragma unroll
        for (int k = 0; k < 11; k++) wr[k] = wp[i * 11 + k];
        float hr[42];
        const float* hp = ht + i * 139 + lq * 32;
#pragma unroll
        for (int k = 0; k < 42; k++) hr[k] = hp[k];
#pragma unroll
        for (int k = 0; k < 11; k++)
#pragma unroll
            for (int j = 0; j < 32; j++) acc[j] += hr[k + j] * wr[k];
    }
    float bsv = bias[o];
    float* op = out + ((size_t)b * 64 + o) * TL + l0 + lq * 32;
    if (accumulate) {
#pragma unroll
        for (int j = 0; j < 32; j++) op[j] += acc[j] + bsv;
    } else {
#pragma unroll
        for (int j = 0; j < 32; j++) op[j] = acc[j] + bsv;
    }
}

// ---------------- transpose [NB][64][TL] -> [TL][NB][64] ----------------
__global__ __launch_bounds__(256) void k_transpose(
    const float* __restrict__ x0, float* __restrict__ X)
{
    __shared__ float t[64 * 65];
    int tid = threadIdx.x;
    int b = blockIdx.x >> 5;
    int t0 = (blockIdx.x & 31) << 6;
    for (int r = 0; r < 16; r++) {
        int idx = tid + 256 * r;
        int c = idx >> 6, tt = idx & 63;
        t[c * 65 + tt] = x0[((size_t)b * 64 + c) * TL + t0 + tt];
    }
    __syncthreads();
    for (int r = 0; r < 16; r++) {
        int idx = tid + 256 * r;
        int tt = idx >> 6, c = idx & 63;
        X[((size_t)(t0 + tt)) * (NB * NH) + b * 64 + c] = t[c * 65 + tt];
    }
}

// ---------------- pipelined 10-layer LSTM (1 barrier/step, superstep=8 handshake) ----------------
__global__ __launch_bounds__(256, 1) void k_lstm(
    const float* __restrict__ X0,
    const float* __restrict__ w_ih, const float* __restrict__ w_hh,
    const float* __restrict__ b_ih, const float* __restrict__ b_hh,
    float* __restrict__ ring, float* __restrict__ final_h, int* prog)
{
    int bid = blockIdx.x;
    int grp = bid & 7;
    int layer = bid >> 3;
    if (grp >= NGRP || layer >= NLAY) return;
    int b0 = grp * GB;
    int tid = threadIdx.x;
    int wv = tid >> 6, lane = tid & 63;
    int l15 = lane & 15, l4 = lane >> 4;
    int u = wv * 16 + l15;

    // double-buffered x(cols 0..63) + h(cols 64..127), hi/lo bf16 split
    __shared__ __align__(16) unsigned short XH[2][16][136];
    __shared__ __align__(16) unsigned short XL[2][16][136];

    // --- weight fragments into registers (persist across all 2048 steps) ---
    bhalf8 Bh[4][4], Bl[4][4];
    float bias_v[4];
#pragma unroll
    for (int nt = 0; nt < 4; nt++) {
        int n = (nt * 4 + wv) * 16 + l15;     // gate row: nt*64 + u
        const float* rih = w_ih + ((size_t)layer * 256 + n) * 64;
        const float* rhh = w_hh + ((size_t)layer * 256 + n) * 64;
        bias_v[nt] = b_ih[layer * 256 + n] + b_hh[layer * 256 + n];
#pragma unroll
        for (int kt = 0; kt < 4; kt++) {
#pragma unroll
            for (int j = 0; j < 8; j++) {
                int k = kt * 32 + l4 * 8 + j;
                float v = (k < 64) ? rih[k] : rhh[k - 64];
                unsigned short hb = f2bf(v);
                float lo = v - bf2f(hb);
                Bh[nt][kt][j] = (short)hb;
                Bl[nt][kt][j] = (short)f2bf(lo);
            }
        }
    }

    // zero h region, both buffers
    for (int idx = tid; idx < 2048; idx += 256) {
        int q = idx >> 10, rw = (idx >> 6) & 15, cc = 64 + (idx & 63);
        XH[q][rw][cc] = 0;
        XL[q][rw][cc] = 0;
    }
    float cst[4] = {0.f, 0.f, 0.f, 0.f};

    int self = layer * NGRP + grp;
    int* p_self = prog + self * 32;
    int* p_prev = prog + (self - NGRP) * 32;
    int* p_next = prog + (self + NGRP) * 32;
    int cached_prev = 0, cached_next = 0;
    const int has_store = (layer < NLAY - 1);
    int brow = tid >> 4;             // (tid*4)>>6
    int cc0 = (tid * 4) & 63;

    // ---- prologue: stage x(0) into buf0, issue prefetch of x(1) ----
    if (tid == 0 && layer > 0) {
        int g = 0, v = 0;
        while ((v = __hip_atomic_load(p_prev, __ATOMIC_ACQUIRE, __HIP_MEMORY_SCOPE_AGENT)) < 8 && ++g < 30000000)
            __builtin_amdgcn_s_sleep(8);
        cached_prev = v;
    }
    __syncthreads();
    f32x4 px;
    {
        const float* s0 = (layer == 0)
            ? X0 + (size_t)b0 * NH + tid * 4
            : ring + ((size_t)(layer - 1) * RING_STEPS) * (NB * NH) + b0 * NH + tid * 4;
        f32x4 p0;
        asm volatile("global_load_dwordx4 %0, %1, off sc0 sc1" : "=&v"(p0) : "v"(s0) : "memory");
        asm volatile("s_waitcnt vmcnt(0)" ::: "memory");
        __builtin_amdgcn_sched_barrier(0);
        bhalf4 hv, lv;
#pragma unroll
        for (int j = 0; j < 4; j++) {
            unsigned short hb = f2bf(p0[j]);
            hv[j] = (short)hb;
            lv[j] = (short)f2bf(p0[j] - bf2f(hb));
        }
        *(bhalf4*)&XH[0][brow][cc0] = hv;
        *(bhalf4*)&XL[0][brow][cc0] = lv;
        const float* s1 = (layer == 0)
            ? X0 + ((size_t)1 * NB + b0) * NH + tid * 4
            : ring + ((size_t)(layer - 1) * RING_STEPS + 1) * (NB * NH) + b0 * NH + tid * 4;
        asm volatile("global_load_dwordx4 %0, %1, off sc0 sc1" : "=&v"(px) : "v"(s1) : "memory");
    }
    __syncthreads();   // drains prefetch (prologue only)

    for (int t0 = 0; t0 < TL; t0 += 8) {
        if (tid == 0) {
            if (layer > 0) {
                int tgt = t0 + 16; if (tgt > TL) tgt = TL;
                if (cached_prev < tgt) {
                    int g = 0, v;
                    while ((v = __hip_atomic_load(p_prev, __ATOMIC_ACQUIRE, __HIP_MEMORY_SCOPE_AGENT)) < tgt && ++g < 30000000)
                        __builtin_amdgcn_s_sleep(8);
                    cached_prev = v;
                }
            }
            if (has_store) {
                int need = t0 + 16 - RING_STEPS;
                if (need > 0 && cached_next < need) {
                    int g = 0, v;
                    while ((v = __hip_atomic_load(p_next, __ATOMIC_ACQUIRE, __HIP_MEMORY_SCOPE_AGENT)) < need && ++g < 30000000)
                        __builtin_amdgcn_s_sleep(8);
                    cached_next = v;
                }
            }
        }
        __syncthreads();

#pragma unroll
        for (int ts = 0; ts < 8; ++ts) {
            const int p = ts & 1, q = p ^ 1;    // t0 is even -> parity of t == parity of ts
            const int t = t0 + ts;

            // ---- gates[16,256] = Xcat @ Wcat^T, 3-term split precision ----
            f32x4 a0 = {0, 0, 0, 0}, a1 = {0, 0, 0, 0}, a2 = {0, 0, 0, 0}, a3 = {0, 0, 0, 0};
#pragma unroll
            for (int kt = 0; kt < 4; kt++) {
                bhalf8 Ah = *(const bhalf8*)&XH[p][l15][kt * 32 + l4 * 8];
                bhalf8 Al = *(const bhalf8*)&XL[p][l15][kt * 32 + l4 * 8];
                a0 = __builtin_amdgcn_mfma_f32_16x16x32_bf16(Ah, Bh[0][kt], a0, 0, 0, 0);
                a1 = __builtin_amdgcn_mfma_f32_16x16x32_bf16(Ah, Bh[1][kt], a1, 0, 0, 0);
                a2 = __builtin_amdgcn_mfma_f32_16x16x32_bf16(Ah, Bh[2][kt], a2, 0, 0, 0);
                a3 = __builtin_amdgcn_mfma_f32_16x16x32_bf16(Ah, Bh[3][kt], a3, 0, 0, 0);
                a0 = __builtin_amdgcn_mfma_f32_16x16x32_bf16(Al, Bh[0][kt], a0, 0, 0, 0);
                a1 = __builtin_amdgcn_mfma_f32_16x16x32_bf16(Al, Bh[1][kt], a1, 0, 0, 0);
                a2 = __builtin_amdgcn_mfma_f32_16x16x32_bf16(Al, Bh[2][kt], a2, 0, 0, 0);
                a3 = __builtin_amdgcn_mfma_f32_16x16x32_bf16(Al, Bh[3][kt], a3, 0, 0, 0);
                a0 = __builtin_amdgcn_mfma_f32_16x16x32_bf16(Ah, Bl[0][kt], a0, 0, 0, 0);
                a1 = __builtin_amdgcn_mfma_f32_16x16x32_bf16(Ah, Bl[1][kt], a1, 0, 0, 0);
                a2 = __builtin_amdgcn_mfma_f32_16x16x32_bf16(Ah, Bl[2][kt], a2, 0, 0, 0);
                a3 = __builtin_amdgcn_mfma_f32_16x16x32_bf16(Ah, Bl[3][kt], a3, 0, 0, 0);
            }

            // ---- lane-local nonlinearity ----
            float hv4[4];
#pragma unroll
            for (int r = 0; r < 4; r++) {
                float gi = a0[r] + bias_v[0];
                float gf = a1[r] + bias_v[1];
                float gg = a2[r] + bias_v[2];
                float go = a3[r] + bias_v[3];
                float c = fast_sigmoid(gf) * cst[r] + fast_sigmoid(gi) * fast_tanh(gg);
                cst[r] = c;
                hv4[r] = fast_sigmoid(go) * fast_tanh(c);
            }

            // ---- phase4: counted vmcnt (ring stores stay in flight), write buf q ----
            if (has_store) { asm volatile("s_waitcnt vmcnt(4)" ::: "memory"); }
            else           { asm volatile("s_waitcnt vmcnt(0)" ::: "memory"); }
            __builtin_amdgcn_sched_barrier(0);
            {
                bhalf4 hv, lv;
#pragma unroll
                for (int j = 0; j < 4; j++) {
                    unsigned short hb = f2bf(px[j]);
                    hv[j] = (short)hb;
                    lv[j] = (short)f2bf(px[j] - bf2f(hb));
                }
                *(bhalf4*)&XH[q][brow][cc0] = hv;
                *(bhalf4*)&XL[q][brow][cc0] = lv;
            }
#pragma unroll
            for (int r = 0; r < 4; r++) {
                int row = l4 * 4 + r;
                unsigned short hb = f2bf(hv4[r]);
                XH[q][row][64 + u] = hb;
                XL[q][row][64 + u] = (unsigned short)f2bf(hv4[r] - bf2f(hb));
            }
            // issue prefetch of x(t+2) BEFORE the ring stores (vmcnt(4) counts from oldest)
            {
                int tt = t + 2; if (tt > TL - 1) tt = TL - 1;
                const float* sp = (layer == 0)
                    ? X0 + ((size_t)tt * NB + b0) * NH + tid * 4
                    : ring + ((size_t)(layer - 1) * RING_STEPS + (tt & (RING_STEPS - 1))) * (NB * NH) + b0 * NH + tid * 4;
                asm volatile("global_load_dwordx4 %0, %1, off sc0 sc1" : "=&v"(px) : "v"(sp) : "memory");
            }
            if (has_store) {
                float* dst = ring + ((size_t)layer * RING_STEPS + (t & (RING_STEPS - 1))) * (NB * NH);
#pragma unroll
                for (int r = 0; r < 4; r++) {
                    float* ap = dst + (b0 + l4 * 4 + r) * NH + u;
                    asm volatile("global_store_dword %0, %1, off sc0 sc1" :: "v"(ap), "v"(hv4[r]) : "memory");
                }
            } else if (t == TL - 1) {
#pragma unroll
                for (int r = 0; r < 4; r++)
                    final_h[(b0 + l4 * 4 + r) * NH + u] = hv4[r];
            }
            asm volatile("s_waitcnt lgkmcnt(0)" ::: "memory");
            __builtin_amdgcn_s_barrier();
            __builtin_amdgcn_sched_barrier(0);
        }

        __syncthreads();   // drain all lanes' ring stores, then publish
        if (tid == 0)
            __hip_atomic_store(p_self, t0 + 8, __ATOMIC_RELEASE, __HIP_MEMORY_SCOPE_AGENT);
    }
}

// ---------------- head: logits + log_softmax ----------------
__global__ void k_head(const float* __restrict__ fh, const float* __restrict__ ow,
                       const float* __restrict__ ob, float* __restrict__ out)
{
    int b = threadIdx.x;
    if (b >= NB) return;
    const float* h = fh + b * NH;
    float l0 = ob[0], l1 = ob[1];
    for (int uu = 0; uu < 64; uu++) { l0 += h[uu] * ow[uu * 2]; l1 += h[uu] * ow[uu * 2 + 1]; }
    float m = fmaxf(l0, l1);
    float s = expf(l0 - m) + expf(l1 - m);
    float ls = m + logf(s);
    out[b * 2] = l0 - ls;
    out[b * 2 + 1] = l1 - ls;
}

extern "C" void kernel_launch(void* const* d_in, const int* in_sizes, int n_in,
                              void* d_out, int out_size, void* d_ws, size_t ws_size,
                              hipStream_t stream) {
    const float* input = (const float*)d_in[0];
    const float* c1w = (const float*)d_in[2];
    const float* c1b = (const float*)d_in[3];
    const float* c2w = (const float*)d_in[4];
    const float* c2b = (const float*)d_in[5];
    const float* bn1g = (const float*)d_in[6];
    const float* bn1b = (const float*)d_in[7];
    const float* bn1m = (const float*)d_in[8];
    const float* bn1v = (const float*)d_in[9];
    const float* rw1 = (const float*)d_in[10];
    const float* rb1 = (const float*)d_in[11];
    const float* bn2g = (const float*)d_in[12];
    const float* bn2b = (const float*)d_in[13];
    const float* bn2m = (const float*)d_in[14];
    const float* bn2v = (const float*)d_in[15];
    const float* rw2 = (const float*)d_in[16];
    const float* rb2 = (const float*)d_in[17];
    const float* wih = (const float*)d_in[18];
    const float* whh = (const float*)d_in[19];
    const float* bih = (const float*)d_in[20];
    const float* bhh = (const float*)d_in[21];
    const float* outw = (const float*)d_in[22];
    const float* outb = (const float*)d_in[23];

    float* ws = (float*)d_ws;
    float* x0buf = ws;                       // [NB][64][TL]
    float* t1buf = x0buf + 8388608;          // [NB][64][TL]
    float* Xbuf  = t1buf + 8388608;          // [TL][NB][NH]
    float* ringb = Xbuf + 8388608;           // [9][128][4096]
    float* fhbuf = ringb + 4718592;          // [NB][NH]
    int*   progb = (int*)(fhbuf + 4096);     // 40 counters, stride 32 ints

    hipMemsetAsync(progb, 0, NLAY * NGRP * 32 * sizeof(int), stream);

    k_frontend<<<2048, 256, 0, stream>>>(input, c1w, c1b, c2w, c2b, x0buf);
    for (int uu = 0; uu < NRESU; uu++) {
        k_resconv<<<1024, 256, 0, stream>>>(x0buf, t1buf, rw1 + uu * 64 * 64 * 11, rb1 + uu * 64,
                                            bn1g + uu * 64, bn1b + uu * 64, bn1m + uu * 64, bn1v + uu * 64, 0);
        k_resconv<<<1024, 256, 0, stream>>>(t1buf, x0buf, rw2 + uu * 64 * 64 * 11, rb2 + uu * 64,
                                            bn2g + uu * 64, bn2b + uu * 64, bn2m + uu * 64, bn2v + uu * 64, 1);
    }
    k_transpose<<<2048, 256, 0, stream>>>(x0buf, Xbuf);
    k_lstm<<<76, 256, 0, stream>>>(Xbuf, wih, whh, bih, bhh, ringb, fhbuf, progb);
    k_head<<<1, 64, 0, stream>>>(fhbuf, outw, outb, (float*)d_out);
}